// Round 8
// baseline (175.652 us; speedup 1.0000x reference)
//
#include <hip/hip_runtime.h>
#include <math.h>

#define S_LEN  2048
#define BATCH  2
#define DM     1024
#define NHEAD  16
#define DHEAD  64
#define WIN    256
#define MROWS  4096

#define PPAD 68     // f32 LDS row stride for attn P

// gemm_qkv tile geometry (R17): 128x96, BK=32, 4 waves as 2x2 (wave 64x48).
// dbuf LDS 28 KB -> 4 blocks/CU resident (grid 32x32 = 1024 = 4/CU) ->
// 16 waves/CU = 4/SIMD. Per wave per K-tile: 7 ds_read_b128 + 12 MFMA.
#define BM 128
#define BN 96
#define BK 32
#define NKT (DM / BK)          // 32 K-tiles

// gemm_out tile geometry (R14): 128x64, BK=64, 4 waves as 2x2 (64x32 wave)
#define OM 128
#define ON 64

typedef __attribute__((ext_vector_type(8))) short bf16x8;
typedef __attribute__((ext_vector_type(4))) float f32x4;

__device__ __forceinline__ unsigned short f2b(float f) {   // RNE
    unsigned int u = __float_as_uint(f);
    return (unsigned short)((u + 0x7fffu + ((u >> 16) & 1u)) >> 16);
}
__device__ __forceinline__ void gld16(const void* g, void* l) {
    __builtin_amdgcn_global_load_lds(
        (const __attribute__((address_space(1))) void*)g,
        (__attribute__((address_space(3))) void*)l, 16, 0, 0);
}
__device__ __forceinline__ bf16x8 pack8(float4 a, float4 b) {
    bf16x8 r;
    r[0] = (short)f2b(a.x); r[1] = (short)f2b(a.y);
    r[2] = (short)f2b(a.z); r[3] = (short)f2b(a.w);
    r[4] = (short)f2b(b.x); r[5] = (short)f2b(b.y);
    r[6] = (short)f2b(b.z); r[7] = (short)f2b(b.w);
    return r;
}

// ---------------------------------------------------------------------------
// R17: weight transpose (z=0..3) + x fp32->bf16 convert (z=4), one launch.
// ---------------------------------------------------------------------------
__global__ __launch_bounds__(256)
void twcvt4(const float* __restrict__ W0, const float* __restrict__ W1,
            const float* __restrict__ W2, const float* __restrict__ W3,
            const float* __restrict__ x,
            unsigned short* __restrict__ T0, unsigned short* __restrict__ T1,
            unsigned short* __restrict__ T2, unsigned short* __restrict__ T3,
            unsigned short* __restrict__ xb)
{
    const int zz = blockIdx.z;
    if (zz == 4) {
        // x convert: 1024 blocks x 256 thr x 16 elems
        const int flat = blockIdx.y * 32 + blockIdx.x;
        const int base = flat * 4096 + threadIdx.x * 4;
#pragma unroll
        for (int p = 0; p < 4; ++p) {
            const int i = base + p * 1024;
            float4 f = *(const float4*)(x + i);
            ushort4 o;
            o.x = f2b(f.x); o.y = f2b(f.y); o.z = f2b(f.z); o.w = f2b(f.w);
            *(ushort4*)(xb + i) = o;
        }
        return;
    }
    const float* W = (zz == 0) ? W0 : (zz == 1) ? W1 : (zz == 2) ? W2 : W3;
    unsigned short* WT = (zz == 0) ? T0 : (zz == 1) ? T1 : (zz == 2) ? T2 : T3;

    __shared__ float t32[32][33];
    const int bx = blockIdx.x * 32;
    const int by = blockIdx.y * 32;
    const int c  = threadIdx.x & 31;
    const int r0 = threadIdx.x >> 5;
#pragma unroll
    for (int p = 0; p < 4; ++p)
        t32[r0 + 8 * p][c] = W[(size_t)(by + r0 + 8 * p) * DM + bx + c];
    __syncthreads();
#pragma unroll
    for (int p = 0; p < 4; ++p)
        WT[(size_t)(bx + r0 + 8 * p) * DM + by + c] = f2b(t32[c][r0 + 8 * p]);
}

// ---------------------------------------------------------------------------
// R17 gemm_qkv: 128x96, BK=32, 4 waves as 2x2 (wave 64x48), dbuf 28 KB LDS
// -> 4 blocks/CU = 16 waves/CU = 4/SIMD. The R12-R16 arc (2 waves/SIMD, 4
// schedule variants) quadruple-nulled at MfmaUtil ~21%; m97's 37% ran at
// 3/SIMD -- wave-level TLP is the untested binding axis. Per-tile drain
// (vmcnt(0)+barrier) is covered by 3 sibling blocks (m114 mechanism).
// Swizzle: R10-proven key (row>>1)&3 on 16B chunks (4 chunks/row at BK=32);
// staging pre-swizzles the GLOBAL source, LDS dest linear; reads XOR the
// same key -> max 2-way bank aliasing (free; measured 0 conflicts R9/R10).
// ---------------------------------------------------------------------------
__global__ __launch_bounds__(256, 4)
void gemm_qkv(const unsigned short* __restrict__ A,
              const unsigned short* __restrict__ BT,
              const float* __restrict__ b0,
              const float* __restrict__ b1,
              const float* __restrict__ b2,
              const float* __restrict__ beta,
              unsigned short* __restrict__ Cb)
{
    __shared__ unsigned short Ab[2][BM * BK];   // 2 x 8 KB
    __shared__ unsigned short Bb[2][BN * BK];   // 2 x 6 KB

    const int t   = threadIdx.x;
    const int ln  = t & 63;
    const int wv  = t >> 6;          // 0..3
    const int wr  = wv >> 1;         // 64-row slice
    const int wc  = wv & 1;          // 48-col slice
    const int m16 = ln & 15;
    const int g   = ln >> 4;         // 0..3
    const int swz = (m16 >> 1) & 3;  // read-side swizzle key (row>>1)&3

    const int rowBase = blockIdx.y * BM;
    const int colBase = blockIdx.x * BN;

    // staging: thread t covers row sr = t>>2, chunk t&3; source chunk
    // pre-swizzled by (sr>>1)&3 (row+64 has the same key: 64 == 0 mod 8).
    const int sr  = t >> 2;                   // 0..63
    const int scx = (t & 3) ^ ((sr >> 1) & 3);
    const size_t gOff = (size_t)sr * DM + scx * 8;
    const int    ldOff = t * 8;               // shorts (t*16 bytes)

    f32x4 acc[4][3];
#pragma unroll
    for (int u = 0; u < 4; ++u)
#pragma unroll
        for (int v = 0; v < 3; ++v)
            acc[u][v] = (f32x4){0.f, 0.f, 0.f, 0.f};

    const unsigned short* aBase = A  + (size_t)rowBase * DM + gOff;
    const unsigned short* bBase = BT + (size_t)colBase * DM + gOff;

    // prologue: stage K-tile 0 into buffer 0
    {
        gld16(aBase,                    &Ab[0][ldOff]);
        gld16(aBase + (size_t)64 * DM,  &Ab[0][2048 + ldOff]);
        gld16(bBase,                    &Bb[0][ldOff]);
        if (t < 128)
            gld16(bBase + (size_t)64 * DM, &Bb[0][2048 + ldOff]);
        asm volatile("s_waitcnt vmcnt(0)" ::: "memory");
        __builtin_amdgcn_s_barrier();
        __builtin_amdgcn_sched_barrier(0);
    }

    for (int kt = 0; kt < NKT; ++kt) {
        const int cur = kt & 1;
        const unsigned short* Ac = Ab[cur];
        const unsigned short* Bc = Bb[cur];
        unsigned short* An = Ab[cur ^ 1];
        unsigned short* Bn = Bb[cur ^ 1];
        const bool hn = (kt < NKT - 1);
        const unsigned short* aS = aBase + (size_t)(kt + 1) * BK;
        const unsigned short* bS = bBase + (size_t)(kt + 1) * BK;

        // ---- stage tile kt+1 first (loads in flight under the MFMAs) ----
        if (hn) {
            gld16(aS,                   &An[ldOff]);
            gld16(aS + (size_t)64 * DM, &An[2048 + ldOff]);
            gld16(bS,                   &Bn[ldOff]);
            if (t < 128)
                gld16(bS + (size_t)64 * DM, &Bn[2048 + ldOff]);
        }

        // ---- fragment reads (7 x ds_read_b128) ----
        bf16x8 af[4], bf[3];
#pragma unroll
        for (int u = 0; u < 4; ++u)
            af[u] = *(const bf16x8*)&Ac[(wr * 64 + u * 16 + m16) * BK + ((g ^ swz) * 8)];
#pragma unroll
        for (int v = 0; v < 3; ++v)
            bf[v] = *(const bf16x8*)&Bc[(wc * 48 + v * 16 + m16) * BK + ((g ^ swz) * 8)];

        __builtin_amdgcn_s_setprio(1);
#pragma unroll
        for (int u = 0; u < 4; ++u)
#pragma unroll
            for (int v = 0; v < 3; ++v)
                acc[u][v] = __builtin_amdgcn_mfma_f32_16x16x32_bf16(
                    af[u], bf[v], acc[u][v], 0, 0, 0);
        __builtin_amdgcn_s_setprio(0);

        if (hn)
            asm volatile("s_waitcnt vmcnt(0)" ::: "memory");
        __builtin_amdgcn_s_barrier();
        __builtin_amdgcn_sched_barrier(0);
    }

    // epilogue — same math as proven kernel; sec per fragment (fragments are
    // 16-col aligned so they never straddle a 1024-col section boundary).
    const int q4 = g * 4;
#pragma unroll
    for (int v = 0; v < 3; ++v) {
        const int col = colBase + wc * 48 + v * 16 + m16;
        const int sec = col >> 10;
        const int h   = (col >> 6) & (NHEAD - 1);
        const int dh  = col & 63;
        if (sec < 2) {
            const float bi = (sec == 0 ? b0 : b1)[col & (DM - 1)];
            const float sc = (sec == 0) ? 0.125f * __expf(-beta[h]) : 1.0f;
            unsigned short* base = Cb + (size_t)sec * MROWS * DM;
#pragma unroll
            for (int u = 0; u < 4; ++u)
#pragma unroll
                for (int r = 0; r < 4; ++r) {
                    const int row = rowBase + wr * 64 + u * 16 + q4 + r;
                    const int s = row >> 1, bb = row & 1;
                    const int z = bb * NHEAD + h;
                    base[((size_t)z * S_LEN + s) * DHEAD + dh] =
                        f2b((acc[u][v][r] + bi) * sc);
                }
        } else {
            unsigned short* vtb = Cb + (size_t)2 * MROWS * DM;
            const float bi = b2[col & (DM - 1)];
#pragma unroll
            for (int u = 0; u < 4; ++u) {
                const int row0 = rowBase + wr * 64 + u * 16 + q4;
                const int s0   = row0 >> 1;
                ushort2 p0, p1;
                p0.x = f2b(acc[u][v][0] + bi);   // bb=0, s0
                p0.y = f2b(acc[u][v][2] + bi);   // bb=0, s0+1
                p1.x = f2b(acc[u][v][1] + bi);   // bb=1, s0
                p1.y = f2b(acc[u][v][3] + bi);   // bb=1, s0+1
                *(ushort2*)(vtb + ((size_t)(h * DHEAD + dh) * S_LEN + s0)) = p0;
                *(ushort2*)(vtb + ((size_t)((NHEAD + h) * DHEAD + dh) * S_LEN + s0)) = p1;
            }
        }
    }
}

// ---------------------------------------------------------------------------
// R14 gemm_out (unchanged): 128x64 tile, BK=64, 4 waves as 2x2 (wave 64x32).
// 512 blocks = 2 blocks/CU. One-barrier counted schedule.
// ---------------------------------------------------------------------------
__global__ __launch_bounds__(256, 2)
void gemm_out(const unsigned short* __restrict__ A,
              const unsigned short* __restrict__ BT,
              const float* __restrict__ bias,
              float* __restrict__ Cf)
{
    __shared__ unsigned short As[2][OM * 64];   // 2 x 16 KB
    __shared__ unsigned short Bs[2][ON * 64];   // 2 x 8 KB

    const int t  = threadIdx.x;
    const int wv = t >> 6, ln = t & 63;
    const int wr = wv >> 1, wc = wv & 1;        // 2x2, wave 64x32
    const int m16 = ln & 15, g = ln >> 4;
    const int sw  = m16 & 7;

    const int rowBase = blockIdx.y * OM;
    const int colBase = blockIdx.x * ON;

    const int sr  = t >> 3;                   // 0..31
    const int scx = (t & 7) ^ (sr & 7);
    const size_t gOff = (size_t)sr * DM + scx * 8;
    const int    ldOff = t * 8;

    f32x4 acc[4][2];
#pragma unroll
    for (int u = 0; u < 4; ++u)
#pragma unroll
        for (int v = 0; v < 2; ++v)
            acc[u][v] = (f32x4){0.f, 0.f, 0.f, 0.f};

    // prologue: stage K-tile 0
    {
        const unsigned short* a0 = A  + (size_t)rowBase * DM + gOff;
        const unsigned short* bt = BT + (size_t)colBase * DM + gOff;
#pragma unroll
        for (int j = 0; j < 4; ++j)
            gld16(a0 + (size_t)(j * 32) * DM, &As[0][j * 2048 + ldOff]);
#pragma unroll
        for (int j = 0; j < 2; ++j)
            gld16(bt + (size_t)(j * 32) * DM, &Bs[0][j * 2048 + ldOff]);
        asm volatile("s_waitcnt vmcnt(0)" ::: "memory");
        __builtin_amdgcn_s_barrier();
        __builtin_amdgcn_sched_barrier(0);
    }

    for (int kt = 0; kt < DM / 64; ++kt) {
        const int cur = kt & 1;
        const unsigned short* Ac = As[cur];
        const unsigned short* Bc = Bs[cur];
        unsigned short* An = As[cur ^ 1];
        unsigned short* Bn = Bs[cur ^ 1];
        const bool hn = (kt < DM / 64 - 1);
        const unsigned short* aS = A  + (size_t)rowBase * DM + (kt + 1) * 64 + gOff;
        const unsigned short* bS = BT + (size_t)colBase * DM + (kt + 1) * 64 + gOff;

        bf16x8 af0[4], bf0[2];
#pragma unroll
        for (int u = 0; u < 4; ++u)
            af0[u] = *(const bf16x8*)&Ac[(wr * 64 + u * 16 + m16) * 64 + ((g ^ sw) * 8)];
#pragma unroll
        for (int v = 0; v < 2; ++v)
            bf0[v] = *(const bf16x8*)&Bc[(wc * 32 + v * 16 + m16) * 64 + ((g ^ sw) * 8)];

        if (hn) {
#pragma unroll
            for (int j = 0; j < 4; ++j)
                gld16(aS + (size_t)(j * 32) * DM, &An[j * 2048 + ldOff]);
#pragma unroll
            for (int j = 0; j < 2; ++j)
                gld16(bS + (size_t)(j * 32) * DM, &Bn[j * 2048 + ldOff]);
        }

        __builtin_amdgcn_s_setprio(1);
#pragma unroll
        for (int u = 0; u < 4; ++u)
#pragma unroll
            for (int v = 0; v < 2; ++v)
                acc[u][v] = __builtin_amdgcn_mfma_f32_16x16x32_bf16(
                    af0[u], bf0[v], acc[u][v], 0, 0, 0);
        __builtin_amdgcn_s_setprio(0);

        bf16x8 af1[4], bf1[2];
#pragma unroll
        for (int u = 0; u < 4; ++u)
            af1[u] = *(const bf16x8*)&Ac[(wr * 64 + u * 16 + m16) * 64 + (((4 | g) ^ sw) * 8)];
#pragma unroll
        for (int v = 0; v < 2; ++v)
            bf1[v] = *(const bf16x8*)&Bc[(wc * 32 + v * 16 + m16) * 64 + (((4 | g) ^ sw) * 8)];

        __builtin_amdgcn_s_setprio(1);
#pragma unroll
        for (int u = 0; u < 4; ++u)
#pragma unroll
            for (int v = 0; v < 2; ++v)
                acc[u][v] = __builtin_amdgcn_mfma_f32_16x16x32_bf16(
                    af1[u], bf1[v], acc[u][v], 0, 0, 0);
        __builtin_amdgcn_s_setprio(0);

        if (hn)
            asm volatile("s_waitcnt vmcnt(0)" ::: "memory");
        __builtin_amdgcn_s_barrier();
        __builtin_amdgcn_sched_barrier(0);
    }

    const int q4 = g * 4;
#pragma unroll
    for (int v = 0; v < 2; ++v) {
        const int col = colBase + wc * 32 + v * 16 + m16;
        const float bi = bias[col];
#pragma unroll
        for (int u = 0; u < 4; ++u)
#pragma unroll
            for (int r = 0; r < 4; ++r) {
                const int row = rowBase + wr * 64 + u * 16 + q4 + r;
                Cf[(size_t)row * DM + col] = acc[u][v][r] + bi;
            }
    }
}

// ---------------------------------------------------------------------------
// R14 attn (unchanged): async dbuf K/V staging, one barrier per tile,
// wave-private P round-trip (lgkm only). No online max (scores bounded).
// ---------------------------------------------------------------------------
__global__ __launch_bounds__(256, 3)
void attn_mfma(const unsigned short* __restrict__ q,
               const unsigned short* __restrict__ k,
               const unsigned short* __restrict__ vt,
               unsigned short* __restrict__ ao)
{
    __shared__ unsigned short Ks[2][64 * 64];   // [key][d-chunk swz]
    __shared__ unsigned short Vs[2][64 * 64];   // [dh][key-chunk swz]
    __shared__ float Ps[64][PPAD];              // [wave*16 + qrow][key]

    const int t   = threadIdx.x;
    const int wv  = t >> 6, ln = t & 63;
    const int m16 = ln & 15, g = ln >> 4;
    const int sw  = m16 & 7;
    const int z   = blockIdx.y;
    const int q0  = blockIdx.x * 64;
    const size_t zbase = (size_t)z * S_LEN * DHEAD;

    const int sr  = t >> 3;                   // 0..31
    const int scx = (t & 7) ^ (sr & 7);
    const unsigned short* kS = k  + zbase + (size_t)sr * DHEAD + scx * 8;
    const unsigned short* vS = vt + ((size_t)z * DHEAD + sr) * S_LEN + scx * 8;
    const int ldOff = t * 8;                  // shorts

    const unsigned short* qrow = q + zbase + (size_t)(q0 + wv * 16 + m16) * DHEAD;
    bf16x8 qf0 = *(const bf16x8*)(qrow + g * 8);
    bf16x8 qf1 = *(const bf16x8*)(qrow + 32 + g * 8);

    f32x4 oacc[4];
#pragma unroll
    for (int v4 = 0; v4 < 4; ++v4) oacc[v4] = (f32x4){0.f, 0.f, 0.f, 0.f};
    float lr[4];
#pragma unroll
    for (int r = 0; r < 4; ++r) lr[r] = 1.f;   // sink: exp(0)

    const int c0 = (blockIdx.x < 4) ? (4 - (int)blockIdx.x) : 0;

    // prologue: stage tile c0 into buffer 0
    {
        const int kb = q0 - 256 + c0 * 64;
        gld16(kS + (size_t)kb * DHEAD,        &Ks[0][ldOff]);
        gld16(kS + (size_t)(kb + 32) * DHEAD, &Ks[0][2048 + ldOff]);
        gld16(vS + kb,                        &Vs[0][ldOff]);
        gld16(vS + (size_t)32 * S_LEN + kb,   &Vs[0][2048 + ldOff]);
        asm volatile("s_waitcnt vmcnt(0)" ::: "memory");
        __builtin_amdgcn_s_barrier();
        __builtin_amdgcn_sched_barrier(0);
    }

    for (int c = c0; c < 5; ++c) {
        const int cur = (c - c0) & 1;
        const int kb  = q0 - 256 + c * 64;
        const bool hn = (c < 4);

        // stage next tile into buf cur^1 (waited at end of this iter)
        if (hn) {
            const int kn = kb + 64;
            gld16(kS + (size_t)kn * DHEAD,        &Ks[cur ^ 1][ldOff]);
            gld16(kS + (size_t)(kn + 32) * DHEAD, &Ks[cur ^ 1][2048 + ldOff]);
            gld16(vS + kn,                        &Vs[cur ^ 1][ldOff]);
            gld16(vS + (size_t)32 * S_LEN + kn,   &Vs[cur ^ 1][2048 + ldOff]);
        }

        // S = Q K^T
        f32x4 sacc[4];
#pragma unroll
        for (int v4 = 0; v4 < 4; ++v4) {
            sacc[v4] = (f32x4){0.f, 0.f, 0.f, 0.f};
            bf16x8 kf0 = *(const bf16x8*)&Ks[cur][(v4 * 16 + m16) * 64 + ((g ^ sw) * 8)];
            sacc[v4] = __builtin_amdgcn_mfma_f32_16x16x32_bf16(qf0, kf0, sacc[v4], 0, 0, 0);
            bf16x8 kf1 = *(const bf16x8*)&Ks[cur][(v4 * 16 + m16) * 64 + (((4 | g) ^ sw) * 8)];
            sacc[v4] = __builtin_amdgcn_mfma_f32_16x16x32_bf16(qf1, kf1, sacc[v4], 0, 0, 0);
        }

        // mask + exp + row-sum (no max): P -> LDS (wave-private rows)
        const bool mhi = (c == 4), mlo = (c == 0);
#pragma unroll
        for (int r = 0; r < 4; ++r) {
            const int ig = q0 + wv * 16 + g * 4 + r;
            float rsum = 0.f;
#pragma unroll
            for (int v4 = 0; v4 < 4; ++v4) {
                const int jg = kb + v4 * 16 + m16;
                float x = sacc[v4][r];
                const bool valid = (!mhi || jg <= ig) && (!mlo || jg >= ig - (WIN - 1));
                x = valid ? x : -1e30f;
                const float pp = __expf(x);     // masked -> exactly 0
                Ps[wv * 16 + g * 4 + r][v4 * 16 + m16] = pp;
                rsum += pp;
            }
#pragma unroll
            for (int off = 1; off < 16; off <<= 1)
                rsum += __shfl_xor(rsum, off, 64);
            lr[r] += rsum;
        }

        // wave-private round-trip: LDS drain only, no block barrier
        asm volatile("s_waitcnt lgkmcnt(0)" ::: "memory");
        __builtin_amdgcn_sched_barrier(0);

        // O += P V
        const float* prow = &Ps[wv * 16 + m16][0];
        bf16x8 pf0 = pack8(*(const float4*)(prow + g * 8),
                           *(const float4*)(prow + g * 8 + 4));
        bf16x8 pf1 = pack8(*(const float4*)(prow + 32 + g * 8),
                           *(const float4*)(prow + 32 + g * 8 + 4));
#pragma unroll
        for (int v4 = 0; v4 < 4; ++v4) {
            bf16x8 vf0 = *(const bf16x8*)&Vs[cur][(v4 * 16 + m16) * 64 + ((g ^ sw) * 8)];
            oacc[v4] = __builtin_amdgcn_mfma_f32_16x16x32_bf16(pf0, vf0, oacc[v4], 0, 0, 0);
            bf16x8 vf1 = *(const bf16x8*)&Vs[cur][(v4 * 16 + m16) * 64 + (((4 | g) ^ sw) * 8)];
            oacc[v4] = __builtin_amdgcn_mfma_f32_16x16x32_bf16(pf1, vf1, oacc[v4], 0, 0, 0);
        }

        if (hn) {
            asm volatile("s_waitcnt vmcnt(0)" ::: "memory");
            __builtin_amdgcn_s_barrier();
            __builtin_amdgcn_sched_barrier(0);
        }
    }

    const int bb = z >> 4, h = z & 15;
#pragma unroll
    for (int r = 0; r < 4; ++r) {
        const int ig  = q0 + wv * 16 + g * 4 + r;
        const float inv = 1.f / lr[r];
#pragma unroll
        for (int v4 = 0; v4 < 4; ++v4)
            ao[(size_t)(ig * BATCH + bb) * DM + h * DHEAD + v4 * 16 + m16] =
                f2b(oacc[v4][r] * inv);
    }
}

// ---------------------------------------------------------------------------
extern "C" void kernel_launch(void* const* d_in, const int* in_sizes, int n_in,
                              void* d_out, int out_size, void* d_ws, size_t ws_size,
                              hipStream_t stream)
{
    const float* x    = (const float*)d_in[0];
    const float* beta = (const float*)d_in[1];
    const float* Wq   = (const float*)d_in[2];
    const float* bq   = (const float*)d_in[3];
    const float* Wk   = (const float*)d_in[4];
    const float* bk   = (const float*)d_in[5];
    const float* Wv   = (const float*)d_in[6];
    const float* bv   = (const float*)d_in[7];
    const float* Wo   = (const float*)d_in[8];
    const float* bo   = (const float*)d_in[9];
    float* out = (float*)d_out;

    unsigned short* w = (unsigned short*)d_ws;
    const size_t seg = (size_t)MROWS * DM;      // 4M elems
    unsigned short* qb  = w;                    // q (z,s,dh)
    unsigned short* kb  = w + seg;              // k (z,s,dh)
    unsigned short* vtb = w + 2 * seg;          // v^T (z,dh,s) -- direct from QKV
    unsigned short* ab  = w + 3 * seg;          // attn out, row-major
    unsigned short* xb  = w + 4 * seg;          // x bf16
    unsigned short* wtq = w + 5 * seg;          // WqT|WkT|WvT|WoT contiguous
    unsigned short* wtk = wtq + (size_t)DM * DM;
    unsigned short* wtv = wtk + (size_t)DM * DM;
    unsigned short* wto = wtv + (size_t)DM * DM;

    // weight transpose (z=0..3) + x convert (z=4), one launch
    twcvt4<<<dim3(32, 32, 5), 256, 0, stream>>>(
        Wq, Wk, Wv, Wo, x, wtq, wtk, wtv, wto, xb);

    // fused Q+K+V projection: 128x96 tiles -> 32x32 = 1024 blocks (4/CU)
    gemm_qkv<<<dim3(3072 / BN, MROWS / BM), 256, 0, stream>>>(
        xb, wtq, bq, bk, bv, beta, qb);

    attn_mfma<<<dim3(S_LEN / 64, BATCH * NHEAD), 256, 0, stream>>>(qb, kb, vtb, ab);

    // output projection: 128x64 tiles -> 16x32 = 512 blocks (2/CU)
    gemm_out<<<dim3(DM / ON, MROWS / OM), 256, 0, stream>>>(ab, wto, bo, out);
}

// Round 10
// 174.810 us; speedup vs baseline: 1.0048x; 1.0048x over previous
//
#include <hip/hip_runtime.h>
#include <math.h>

#define S_LEN  2048
#define BATCH  2
#define DM     1024
#define NHEAD  16
#define DHEAD  64
#define WIN    256
#define MROWS  4096

#define PPAD 68     // f32 LDS row stride for attn P

// gemm_qkv tile geometry (R19 = m201-faithful, round-granular ledger):
// 256x256, BK=64, 8 waves as 2M x 4N (wave 128x64, acc[8][4]).
// LDS 128 KB dbuf. Grid 12x16 = 192 blocks.
#define BM 256
#define BN 256
#define BK 64
#define NKT (DM / BK)          // 16 K-steps

// gemm_out tile geometry (R14): 128x64, BK=64, 4 waves as 2x2 (64x32 wave)
#define OM 128
#define ON 64

typedef __attribute__((ext_vector_type(8))) short bf16x8;
typedef __attribute__((ext_vector_type(4))) float f32x4;

__device__ __forceinline__ unsigned short f2b(float f) {   // RNE
    unsigned int u = __float_as_uint(f);
    return (unsigned short)((u + 0x7fffu + ((u >> 16) & 1u)) >> 16);
}
__device__ __forceinline__ void gld16(const void* g, void* l) {
    __builtin_amdgcn_global_load_lds(
        (const __attribute__((address_space(1))) void*)g,
        (__attribute__((address_space(3))) void*)l, 16, 0, 0);
}
__device__ __forceinline__ bf16x8 pack8(float4 a, float4 b) {
    bf16x8 r;
    r[0] = (short)f2b(a.x); r[1] = (short)f2b(a.y);
    r[2] = (short)f2b(a.z); r[3] = (short)f2b(a.w);
    r[4] = (short)f2b(b.x); r[5] = (short)f2b(b.y);
    r[6] = (short)f2b(b.z); r[7] = (short)f2b(b.w);
    return r;
}

// ---------------------------------------------------------------------------
// R17: weight transpose (z=0..3) + x fp32->bf16 convert (z=4), one launch.
// ---------------------------------------------------------------------------
__global__ __launch_bounds__(256)
void twcvt4(const float* __restrict__ W0, const float* __restrict__ W1,
            const float* __restrict__ W2, const float* __restrict__ W3,
            const float* __restrict__ x,
            unsigned short* __restrict__ T0, unsigned short* __restrict__ T1,
            unsigned short* __restrict__ T2, unsigned short* __restrict__ T3,
            unsigned short* __restrict__ xb)
{
    const int zz = blockIdx.z;
    if (zz == 4) {
        const int flat = blockIdx.y * 32 + blockIdx.x;
        const int base = flat * 4096 + threadIdx.x * 4;
#pragma unroll
        for (int p = 0; p < 4; ++p) {
            const int i = base + p * 1024;
            float4 f = *(const float4*)(x + i);
            ushort4 o;
            o.x = f2b(f.x); o.y = f2b(f.y); o.z = f2b(f.z); o.w = f2b(f.w);
            *(ushort4*)(xb + i) = o;
        }
        return;
    }
    const float* W = (zz == 0) ? W0 : (zz == 1) ? W1 : (zz == 2) ? W2 : W3;
    unsigned short* WT = (zz == 0) ? T0 : (zz == 1) ? T1 : (zz == 2) ? T2 : T3;

    __shared__ float t32[32][33];
    const int bx = blockIdx.x * 32;
    const int by = blockIdx.y * 32;
    const int c  = threadIdx.x & 31;
    const int r0 = threadIdx.x >> 5;
#pragma unroll
    for (int p = 0; p < 4; ++p)
        t32[r0 + 8 * p][c] = W[(size_t)(by + r0 + 8 * p) * DM + bx + c];
    __syncthreads();
#pragma unroll
    for (int p = 0; p < 4; ++p)
        WT[(size_t)(bx + r0 + 8 * p) * DM + by + c] = f2b(t32[c][r0 + 8 * p]);
}

// ---------------------------------------------------------------------------
// R19 gemm_qkv: m201-faithful 4-phase template, ROUND-GRANULAR wait ledger
// (fixes R18's race: absmax 0.109).
//
// Read footprint per phase across ALL waves (wave = 128x64 at (wr,wc)):
//   ph0 ds_reads: A rounds {0,2} (wr=0 rows 0-63, wr=1 rows 128-191),
//                 B rounds {0,1,2,3} (4 wc slices x cols +0..31)
//   ph1 ds_reads: B rounds {0,1,2,3} (cols +32..63)
//   ph2 ds_reads: A rounds {1,3}
//   ph3: register-only (afr from ph2, bfr[0..1] from ph0)
//
// Staging of tile kt+1 during iter kt (issue order = force order):
//   ph0: B_r0,B_r1   ph1: B_r2,B_r3   ph2: A_r0,A_r2   ph3: A_r1,A_r3
// Ledger (per-wave outstanding):
//   end-ph1: 2 stale (A1,A3 of kt) + 4 new B -> vmcnt(4) forces A1,A3[kt]
//            (needed by ph2 reads); vmcnt(0) on last iter.
//   end-ph3: 8 outstanding -> vmcnt(2) forces B0-3,A0,A2 of kt+1 (needed by
//            next ph0/ph1), leaves A1,A3[kt+1] in flight. Never drains
//            mid-loop. Every wait is followed by s_barrier (cross-wave
//            landing guarantee) + sched_barrier(0) (rule #18).
// No WAR: stage buf != read buf; all reads of a buffer drain (lgkmcnt(0))
// before the end-of-iter barrier that precedes any restaging of it.
// Chunk-XOR swizzle (0 conflicts measured R9-R17) on staging SOURCE + read.
// ---------------------------------------------------------------------------
__global__ __launch_bounds__(512, 2)
void gemm_qkv(const unsigned short* __restrict__ A,
              const unsigned short* __restrict__ BT,
              const float* __restrict__ b0,
              const float* __restrict__ b1,
              const float* __restrict__ b2,
              const float* __restrict__ beta,
              unsigned short* __restrict__ Cb)
{
    __shared__ unsigned short Ab[2][BM * BK];   // 2 x 32 KB
    __shared__ unsigned short Bb[2][BN * BK];   // 2 x 32 KB

    const int t   = threadIdx.x;
    const int ln  = t & 63;
    const int wv  = t >> 6;          // 0..7
    const int wr  = wv >> 2;         // M-half of block (128 rows)
    const int wc  = wv & 3;          // 64-col slice
    const int m16 = ln & 15;
    const int g   = ln >> 4;         // 0..3
    const int sw  = m16 & 7;         // read-side swizzle key (row & 7)

    const int rowBase = blockIdx.y * BM;
    const int colBase = blockIdx.x * BN;

    // staging: thread t covers row sr = t>>3 (0..63) of a 64-row round,
    // 16B chunk (t&7) pre-swizzled by (sr&7); LDS dest linear (t*16B).
    const int sr  = t >> 3;
    const int scx = (t & 7) ^ (sr & 7);
    const size_t gOff = (size_t)sr * DM + scx * 8;
    const int    ldOff = t * 8;               // shorts (t*16 bytes)

    const unsigned short* aBase = A  + (size_t)rowBase * DM + gOff;
    const unsigned short* bBase = BT + (size_t)colBase * DM + gOff;

    f32x4 acc[8][4];
#pragma unroll
    for (int u = 0; u < 8; ++u)
#pragma unroll
        for (int v = 0; v < 4; ++v)
            acc[u][v] = (f32x4){0.f, 0.f, 0.f, 0.f};

    // per-round staging: round r = rows r*64..r*64+63 of the tile
#define STAGE_AR(buf, kt1, r)                                                 \
    gld16(aBase + (size_t)(kt1) * BK + (size_t)((r) * 64) * DM,               \
          &Ab[buf][(r) * 4096 + ldOff])
#define STAGE_BR(buf, kt1, r)                                                 \
    gld16(bBase + (size_t)(kt1) * BK + (size_t)((r) * 64) * DM,               \
          &Bb[buf][(r) * 4096 + ldOff])

    // prologue: tile 0 in force order B0,B1,B2,B3,A0,A2,A1,A3; vmcnt(2)
    // leaves A1,A3 in flight (not needed until ph2).
    STAGE_BR(0, 0, 0); STAGE_BR(0, 0, 1); STAGE_BR(0, 0, 2); STAGE_BR(0, 0, 3);
    STAGE_AR(0, 0, 0); STAGE_AR(0, 0, 2);
    STAGE_AR(0, 0, 1); STAGE_AR(0, 0, 3);
    asm volatile("s_waitcnt vmcnt(2)" ::: "memory");
    __builtin_amdgcn_s_barrier();
    __builtin_amdgcn_sched_barrier(0);

    bf16x8 afr[4][2], bfr[4][2];

    for (int kt = 0; kt < NKT; ++kt) {
        const int cur = kt & 1, nxt = cur ^ 1;
        const unsigned short* Ac = Ab[cur];
        const unsigned short* Bc = Bb[cur];
        const bool hn = (kt < NKT - 1);

        // ---------------- ph0: quadrant (0,0) ------------------------------
#pragma unroll
        for (int u = 0; u < 4; ++u) {
            const int ro = (wr * 128 + u * 16 + m16) * BK;
            afr[u][0] = *(const bf16x8*)&Ac[ro + ((g ^ sw) * 8)];
            afr[u][1] = *(const bf16x8*)&Ac[ro + (((4 | g) ^ sw) * 8)];
        }
#pragma unroll
        for (int v = 0; v < 2; ++v) {
            const int ro = (wc * 64 + v * 16 + m16) * BK;
            bfr[v][0] = *(const bf16x8*)&Bc[ro + ((g ^ sw) * 8)];
            bfr[v][1] = *(const bf16x8*)&Bc[ro + (((4 | g) ^ sw) * 8)];
        }
        if (hn) { STAGE_BR(nxt, kt + 1, 0); STAGE_BR(nxt, kt + 1, 1); }
        __builtin_amdgcn_s_barrier();
        asm volatile("s_waitcnt lgkmcnt(0)" ::: "memory");
        __builtin_amdgcn_sched_barrier(0);
        __builtin_amdgcn_s_setprio(1);
#pragma unroll
        for (int u = 0; u < 4; ++u)
#pragma unroll
            for (int v = 0; v < 2; ++v) {
                acc[u][v] = __builtin_amdgcn_mfma_f32_16x16x32_bf16(
                    afr[u][0], bfr[v][0], acc[u][v], 0, 0, 0);
                acc[u][v] = __builtin_amdgcn_mfma_f32_16x16x32_bf16(
                    afr[u][1], bfr[v][1], acc[u][v], 0, 0, 0);
            }
        __builtin_amdgcn_s_setprio(0);
        __builtin_amdgcn_s_barrier();
        __builtin_amdgcn_sched_barrier(0);

        // ---------------- ph1: quadrant (0,1) ------------------------------
#pragma unroll
        for (int v = 0; v < 2; ++v) {
            const int ro = (wc * 64 + 32 + v * 16 + m16) * BK;
            bfr[2 + v][0] = *(const bf16x8*)&Bc[ro + ((g ^ sw) * 8)];
            bfr[2 + v][1] = *(const bf16x8*)&Bc[ro + (((4 | g) ^ sw) * 8)];
        }
        if (hn) { STAGE_BR(nxt, kt + 1, 2); STAGE_BR(nxt, kt + 1, 3); }
        __builtin_amdgcn_s_barrier();
        asm volatile("s_waitcnt lgkmcnt(0)" ::: "memory");
        __builtin_amdgcn_sched_barrier(0);
        __builtin_amdgcn_s_setprio(1);
#pragma unroll
        for (int u = 0; u < 4; ++u)
#pragma unroll
            for (int v = 0; v < 2; ++v) {
                acc[u][2 + v] = __builtin_amdgcn_mfma_f32_16x16x32_bf16(
                    afr[u][0], bfr[2 + v][0], acc[u][2 + v], 0, 0, 0);
                acc[u][2 + v] = __builtin_amdgcn_mfma_f32_16x16x32_bf16(
                    afr[u][1], bfr[2 + v][1], acc[u][2 + v], 0, 0, 0);
            }
        __builtin_amdgcn_s_setprio(0);
        // force A1,A3 of tile kt (issued ph3 of iter kt-1) before ph2 reads
        if (hn)
            asm volatile("s_waitcnt vmcnt(4)" ::: "memory");
        else
            asm volatile("s_waitcnt vmcnt(0)" ::: "memory");
        __builtin_amdgcn_s_barrier();
        __builtin_amdgcn_sched_barrier(0);

        // ---------------- ph2: quadrant (1,1) ------------------------------
#pragma unroll
        for (int u = 0; u < 4; ++u) {
            const int ro = (wr * 128 + 64 + u * 16 + m16) * BK;
            afr[u][0] = *(const bf16x8*)&Ac[ro + ((g ^ sw) * 8)];
            afr[u][1] = *(const bf16x8*)&Ac[ro + (((4 | g) ^ sw) * 8)];
        }
        if (hn) { STAGE_AR(nxt, kt + 1, 0); STAGE_AR(nxt, kt + 1, 2); }
        __builtin_amdgcn_s_barrier();
        asm volatile("s_waitcnt lgkmcnt(0)" ::: "memory");
        __builtin_amdgcn_sched_barrier(0);
        __builtin_amdgcn_s_setprio(1);
#pragma unroll
        for (int u = 0; u < 4; ++u)
#pragma unroll
            for (int v = 0; v < 2; ++v) {
                acc[4 + u][2 + v] = __builtin_amdgcn_mfma_f32_16x16x32_bf16(
                    afr[u][0], bfr[2 + v][0], acc[4 + u][2 + v], 0, 0, 0);
                acc[4 + u][2 + v] = __builtin_amdgcn_mfma_f32_16x16x32_bf16(
                    afr[u][1], bfr[2 + v][1], acc[4 + u][2 + v], 0, 0, 0);
            }
        __builtin_amdgcn_s_setprio(0);
        __builtin_amdgcn_s_barrier();
        __builtin_amdgcn_sched_barrier(0);

        // ---------------- ph3: quadrant (1,0) ------------------------------
        if (hn) { STAGE_AR(nxt, kt + 1, 1); STAGE_AR(nxt, kt + 1, 3); }
        __builtin_amdgcn_s_barrier();
        __builtin_amdgcn_sched_barrier(0);
        __builtin_amdgcn_s_setprio(1);
#pragma unroll
        for (int u = 0; u < 4; ++u)
#pragma unroll
            for (int v = 0; v < 2; ++v) {
                acc[4 + u][v] = __builtin_amdgcn_mfma_f32_16x16x32_bf16(
                    afr[u][0], bfr[v][0], acc[4 + u][v], 0, 0, 0);
                acc[4 + u][v] = __builtin_amdgcn_mfma_f32_16x16x32_bf16(
                    afr[u][1], bfr[v][1], acc[4 + u][v], 0, 0, 0);
            }
        __builtin_amdgcn_s_setprio(0);
        // force B0-3,A0,A2 of tile kt+1; leave its A1,A3 in flight
        if (hn)
            asm volatile("s_waitcnt vmcnt(2)" ::: "memory");
        __builtin_amdgcn_s_barrier();
        __builtin_amdgcn_sched_barrier(0);
    }
#undef STAGE_AR
#undef STAGE_BR

    // epilogue — same math as proven kernel; sec per fragment (wave-uniform).
    const int q4 = g * 4;
#pragma unroll
    for (int v = 0; v < 4; ++v) {
        const int col = colBase + wc * 64 + v * 16 + m16;
        const int sec = col >> 10;
        const int h   = (col >> 6) & (NHEAD - 1);
        const int dh  = col & 63;
        if (sec < 2) {
            const float bi = (sec == 0 ? b0 : b1)[col & (DM - 1)];
            const float sc = (sec == 0) ? 0.125f * __expf(-beta[h]) : 1.0f;
            unsigned short* base = Cb + (size_t)sec * MROWS * DM;
#pragma unroll
            for (int u = 0; u < 8; ++u)
#pragma unroll
                for (int r = 0; r < 4; ++r) {
                    const int row = rowBase + wr * 128 + u * 16 + q4 + r;
                    const int s = row >> 1, bb = row & 1;
                    const int z = bb * NHEAD + h;
                    base[((size_t)z * S_LEN + s) * DHEAD + dh] =
                        f2b((acc[u][v][r] + bi) * sc);
                }
        } else {
            unsigned short* vtb = Cb + (size_t)2 * MROWS * DM;
            const float bi = b2[col & (DM - 1)];
#pragma unroll
            for (int u = 0; u < 8; ++u) {
                const int row0 = rowBase + wr * 128 + u * 16 + q4;
                const int s0   = row0 >> 1;
                ushort2 p0, p1;
                p0.x = f2b(acc[u][v][0] + bi);   // bb=0, s0
                p0.y = f2b(acc[u][v][2] + bi);   // bb=0, s0+1
                p1.x = f2b(acc[u][v][1] + bi);   // bb=1, s0
                p1.y = f2b(acc[u][v][3] + bi);   // bb=1, s0+1
                *(ushort2*)(vtb + ((size_t)(h * DHEAD + dh) * S_LEN + s0)) = p0;
                *(ushort2*)(vtb + ((size_t)((NHEAD + h) * DHEAD + dh) * S_LEN + s0)) = p1;
            }
        }
    }
}

// ---------------------------------------------------------------------------
// R14 gemm_out (unchanged): 128x64 tile, BK=64, 4 waves as 2x2 (wave 64x32).
// 512 blocks = 2 blocks/CU. One-barrier counted schedule.
// ---------------------------------------------------------------------------
__global__ __launch_bounds__(256, 2)
void gemm_out(const unsigned short* __restrict__ A,
              const unsigned short* __restrict__ BT,
              const float* __restrict__ bias,
              float* __restrict__ Cf)
{
    __shared__ unsigned short As[2][OM * 64];   // 2 x 16 KB
    __shared__ unsigned short Bs[2][ON * 64];   // 2 x 8 KB

    const int t  = threadIdx.x;
    const int wv = t >> 6, ln = t & 63;
    const int wr = wv >> 1, wc = wv & 1;        // 2x2, wave 64x32
    const int m16 = ln & 15, g = ln >> 4;
    const int sw  = m16 & 7;

    const int rowBase = blockIdx.y * OM;
    const int colBase = blockIdx.x * ON;

    const int sr  = t >> 3;                   // 0..31
    const int scx = (t & 7) ^ (sr & 7);
    const size_t gOff = (size_t)sr * DM + scx * 8;
    const int    ldOff = t * 8;

    f32x4 acc[4][2];
#pragma unroll
    for (int u = 0; u < 4; ++u)
#pragma unroll
        for (int v = 0; v < 2; ++v)
            acc[u][v] = (f32x4){0.f, 0.f, 0.f, 0.f};

    // prologue: stage K-tile 0
    {
        const unsigned short* a0 = A  + (size_t)rowBase * DM + gOff;
        const unsigned short* bt = BT + (size_t)colBase * DM + gOff;
#pragma unroll
        for (int j = 0; j < 4; ++j)
            gld16(a0 + (size_t)(j * 32) * DM, &As[0][j * 2048 + ldOff]);
#pragma unroll
        for (int j = 0; j < 2; ++j)
            gld16(bt + (size_t)(j * 32) * DM, &Bs[0][j * 2048 + ldOff]);
        asm volatile("s_waitcnt vmcnt(0)" ::: "memory");
        __builtin_amdgcn_s_barrier();
        __builtin_amdgcn_sched_barrier(0);
    }

    for (int kt = 0; kt < DM / 64; ++kt) {
        const int cur = kt & 1;
        const unsigned short* Ac = As[cur];
        const unsigned short* Bc = Bs[cur];
        unsigned short* An = As[cur ^ 1];
        unsigned short* Bn = Bs[cur ^ 1];
        const bool hn = (kt < DM / 64 - 1);
        const unsigned short* aS = A  + (size_t)rowBase * DM + (kt + 1) * 64 + gOff;
        const unsigned short* bS = BT + (size_t)colBase * DM + (kt + 1) * 64 + gOff;

        bf16x8 af0[4], bf0[2];
#pragma unroll
        for (int u = 0; u < 4; ++u)
            af0[u] = *(const bf16x8*)&Ac[(wr * 64 + u * 16 + m16) * 64 + ((g ^ sw) * 8)];
#pragma unroll
        for (int v = 0; v < 2; ++v)
            bf0[v] = *(const bf16x8*)&Bc[(wc * 32 + v * 16 + m16) * 64 + ((g ^ sw) * 8)];

        if (hn) {
#pragma unroll
            for (int j = 0; j < 4; ++j)
                gld16(aS + (size_t)(j * 32) * DM, &An[j * 2048 + ldOff]);
#pragma unroll
            for (int j = 0; j < 2; ++j)
                gld16(bS + (size_t)(j * 32) * DM, &Bn[j * 2048 + ldOff]);
        }

        __builtin_amdgcn_s_setprio(1);
#pragma unroll
        for (int u = 0; u < 4; ++u)
#pragma unroll
            for (int v = 0; v < 2; ++v)
                acc[u][v] = __builtin_amdgcn_mfma_f32_16x16x32_bf16(
                    af0[u], bf0[v], acc[u][v], 0, 0, 0);
        __builtin_amdgcn_s_setprio(0);

        bf16x8 af1[4], bf1[2];
#pragma unroll
        for (int u = 0; u < 4; ++u)
            af1[u] = *(const bf16x8*)&Ac[(wr * 64 + u * 16 + m16) * 64 + (((4 | g) ^ sw) * 8)];
#pragma unroll
        for (int v = 0; v < 2; ++v)
            bf1[v] = *(const bf16x8*)&Bc[(wc * 32 + v * 16 + m16) * 64 + (((4 | g) ^ sw) * 8)];

        __builtin_amdgcn_s_setprio(1);
#pragma unroll
        for (int u = 0; u < 4; ++u)
#pragma unroll
            for (int v = 0; v < 2; ++v)
                acc[u][v] = __builtin_amdgcn_mfma_f32_16x16x32_bf16(
                    af1[u], bf1[v], acc[u][v], 0, 0, 0);
        __builtin_amdgcn_s_setprio(0);

        if (hn)
            asm volatile("s_waitcnt vmcnt(0)" ::: "memory");
        __builtin_amdgcn_s_barrier();
        __builtin_amdgcn_sched_barrier(0);
    }

    const int q4 = g * 4;
#pragma unroll
    for (int v = 0; v < 2; ++v) {
        const int col = colBase + wc * 32 + v * 16 + m16;
        const float bi = bias[col];
#pragma unroll
        for (int u = 0; u < 4; ++u)
#pragma unroll
            for (int r = 0; r < 4; ++r) {
                const int row = rowBase + wr * 64 + u * 16 + q4 + r;
                Cf[(size_t)row * DM + col] = acc[u][v][r] + bi;
            }
    }
}

// ---------------------------------------------------------------------------
// R14 attn (unchanged): async dbuf K/V staging, one barrier per tile,
// wave-private P round-trip (lgkm only). No online max (scores bounded).
// ---------------------------------------------------------------------------
__global__ __launch_bounds__(256, 3)
void attn_mfma(const unsigned short* __restrict__ q,
               const unsigned short* __restrict__ k,
               const unsigned short* __restrict__ vt,
               unsigned short* __restrict__ ao)
{
    __shared__ unsigned short Ks[2][64 * 64];   // [key][d-chunk swz]
    __shared__ unsigned short Vs[2][64 * 64];   // [dh][key-chunk swz]
    __shared__ float Ps[64][PPAD];              // [wave*16 + qrow][key]

    const int t   = threadIdx.x;
    const int wv  = t >> 6, ln = t & 63;
    const int m16 = ln & 15, g = ln >> 4;
    const int sw  = m16 & 7;
    const int z   = blockIdx.y;
    const int q0  = blockIdx.x * 64;
    const size_t zbase = (size_t)z * S_LEN * DHEAD;

    const int sr  = t >> 3;                   // 0..31
    const int scx = (t & 7) ^ (sr & 7);
    const unsigned short* kS = k  + zbase + (size_t)sr * DHEAD + scx * 8;
    const unsigned short* vS = vt + ((size_t)z * DHEAD + sr) * S_LEN + scx * 8;
    const int ldOff = t * 8;                  // shorts

    const unsigned short* qrow = q + zbase + (size_t)(q0 + wv * 16 + m16) * DHEAD;
    bf16x8 qf0 = *(const bf16x8*)(qrow + g * 8);
    bf16x8 qf1 = *(const bf16x8*)(qrow + 32 + g * 8);

    f32x4 oacc[4];
#pragma unroll
    for (int v4 = 0; v4 < 4; ++v4) oacc[v4] = (f32x4){0.f, 0.f, 0.f, 0.f};
    float lr[4];
#pragma unroll
    for (int r = 0; r < 4; ++r) lr[r] = 1.f;   // sink: exp(0)

    const int c0 = (blockIdx.x < 4) ? (4 - (int)blockIdx.x) : 0;

    // prologue: stage tile c0 into buffer 0
    {
        const int kb = q0 - 256 + c0 * 64;
        gld16(kS + (size_t)kb * DHEAD,        &Ks[0][ldOff]);
        gld16(kS + (size_t)(kb + 32) * DHEAD, &Ks[0][2048 + ldOff]);
        gld16(vS + kb,                        &Vs[0][ldOff]);
        gld16(vS + (size_t)32 * S_LEN + kb,   &Vs[0][2048 + ldOff]);
        asm volatile("s_waitcnt vmcnt(0)" ::: "memory");
        __builtin_amdgcn_s_barrier();
        __builtin_amdgcn_sched_barrier(0);
    }

    for (int c = c0; c < 5; ++c) {
        const int cur = (c - c0) & 1;
        const int kb  = q0 - 256 + c * 64;
        const bool hn = (c < 4);

        // stage next tile into buf cur^1 (waited at end of this iter)
        if (hn) {
            const int kn = kb + 64;
            gld16(kS + (size_t)kn * DHEAD,        &Ks[cur ^ 1][ldOff]);
            gld16(kS + (size_t)(kn + 32) * DHEAD, &Ks[cur ^ 1][2048 + ldOff]);
            gld16(vS + kn,                        &Vs[cur ^ 1][ldOff]);
            gld16(vS + (size_t)32 * S_LEN + kn,   &Vs[cur ^ 1][2048 + ldOff]);
        }

        // S = Q K^T
        f32x4 sacc[4];
#pragma unroll
        for (int v4 = 0; v4 < 4; ++v4) {
            sacc[v4] = (f32x4){0.f, 0.f, 0.f, 0.f};
            bf16x8 kf0 = *(const bf16x8*)&Ks[cur][(v4 * 16 + m16) * 64 + ((g ^ sw) * 8)];
            sacc[v4] = __builtin_amdgcn_mfma_f32_16x16x32_bf16(qf0, kf0, sacc[v4], 0, 0, 0);
            bf16x8 kf1 = *(const bf16x8*)&Ks[cur][(v4 * 16 + m16) * 64 + (((4 | g) ^ sw) * 8)];
            sacc[v4] = __builtin_amdgcn_mfma_f32_16x16x32_bf16(qf1, kf1, sacc[v4], 0, 0, 0);
        }

        // mask + exp + row-sum (no max): P -> LDS (wave-private rows)
        const bool mhi = (c == 4), mlo = (c == 0);
#pragma unroll
        for (int r = 0; r < 4; ++r) {
            const int ig = q0 + wv * 16 + g * 4 + r;
            float rsum = 0.f;
#pragma unroll
            for (int v4 = 0; v4 < 4; ++v4) {
                const int jg = kb + v4 * 16 + m16;
                float x = sacc[v4][r];
                const bool valid = (!mhi || jg <= ig) && (!mlo || jg >= ig - (WIN - 1));
                x = valid ? x : -1e30f;
                const float pp = __expf(x);     // masked -> exactly 0
                Ps[wv * 16 + g * 4 + r][v4 * 16 + m16] = pp;
                rsum += pp;
            }
#pragma unroll
            for (int off = 1; off < 16; off <<= 1)
                rsum += __shfl_xor(rsum, off, 64);
            lr[r] += rsum;
        }

        // wave-private round-trip: LDS drain only, no block barrier
        asm volatile("s_waitcnt lgkmcnt(0)" ::: "memory");
        __builtin_amdgcn_sched_barrier(0);

        // O += P V
        const float* prow = &Ps[wv * 16 + m16][0];
        bf16x8 pf0 = pack8(*(const float4*)(prow + g * 8),
                           *(const float4*)(prow + g * 8 + 4));
        bf16x8 pf1 = pack8(*(const float4*)(prow + 32 + g * 8),
                           *(const float4*)(prow + 32 + g * 8 + 4));
#pragma unroll
        for (int v4 = 0; v4 < 4; ++v4) {
            bf16x8 vf0 = *(const bf16x8*)&Vs[cur][(v4 * 16 + m16) * 64 + ((g ^ sw) * 8)];
            oacc[v4] = __builtin_amdgcn_mfma_f32_16x16x32_bf16(pf0, vf0, oacc[v4], 0, 0, 0);
            bf16x8 vf1 = *(const bf16x8*)&Vs[cur][(v4 * 16 + m16) * 64 + (((4 | g) ^ sw) * 8)];
            oacc[v4] = __builtin_amdgcn_mfma_f32_16x16x32_bf16(pf1, vf1, oacc[v4], 0, 0, 0);
        }

        if (hn) {
            asm volatile("s_waitcnt vmcnt(0)" ::: "memory");
            __builtin_amdgcn_s_barrier();
            __builtin_amdgcn_sched_barrier(0);
        }
    }

    const int bb = z >> 4, h = z & 15;
#pragma unroll
    for (int r = 0; r < 4; ++r) {
        const int ig  = q0 + wv * 16 + g * 4 + r;
        const float inv = 1.f / lr[r];
#pragma unroll
        for (int v4 = 0; v4 < 4; ++v4)
            ao[(size_t)(ig * BATCH + bb) * DM + h * DHEAD + v4 * 16 + m16] =
                f2b(oacc[v4][r] * inv);
    }
}

// ---------------------------------------------------------------------------
extern "C" void kernel_launch(void* const* d_in, const int* in_sizes, int n_in,
                              void* d_out, int out_size, void* d_ws, size_t ws_size,
                              hipStream_t stream)
{
    const float* x    = (const float*)d_in[0];
    const float* beta = (const float*)d_in[1];
    const float* Wq   = (const float*)d_in[2];
    const float* bq   = (const float*)d_in[3];
    const float* Wk   = (const float*)d_in[4];
    const float* bk   = (const float*)d_in[5];
    const float* Wv   = (const float*)d_in[6];
    const float* bv   = (const float*)d_in[7];
    const float* Wo   = (const float*)d_in[8];
    const float* bo   = (const float*)d_in[9];
    float* out = (float*)d_out;

    unsigned short* w = (unsigned short*)d_ws;
    const size_t seg = (size_t)MROWS * DM;      // 4M elems
    unsigned short* qb  = w;                    // q (z,s,dh)
    unsigned short* kb  = w + seg;              // k (z,s,dh)
    unsigned short* vtb = w + 2 * seg;          // v^T (z,dh,s) -- direct from QKV
    unsigned short* ab  = w + 3 * seg;          // attn out, row-major
    unsigned short* xb  = w + 4 * seg;          // x bf16
    unsigned short* wtq = w + 5 * seg;          // WqT|WkT|WvT|WoT contiguous
    unsigned short* wtk = wtq + (size_t)DM * DM;
    unsigned short* wtv = wtk + (size_t)DM * DM;
    unsigned short* wto = wtv + (size_t)DM * DM;

    // weight transpose (z=0..3) + x convert (z=4), one launch
    twcvt4<<<dim3(32, 32, 5), 256, 0, stream>>>(
        Wq, Wk, Wv, Wo, x, wtq, wtk, wtv, wto, xb);

    // fused Q+K+V projection: 256x256 tiles -> 12x16 = 192 blocks (1/CU)
    gemm_qkv<<<dim3(3072 / BN, MROWS / BM), 512, 0, stream>>>(
        xb, wtq, bq, bk, bv, beta, qb);

    attn_mfma<<<dim3(S_LEN / 64, BATCH * NHEAD), 256, 0, stream>>>(qb, kb, vtb, ab);

    // output projection: 128x64 tiles -> 16x32 = 512 blocks (2/CU)
    gemm_out<<<dim3(DM / ON, MROWS / OM), 256, 0, stream>>>(ab, wto, bo, out);
}

// Round 11
// 169.514 us; speedup vs baseline: 1.0362x; 1.0312x over previous
//
#include <hip/hip_runtime.h>
#include <math.h>

#define S_LEN  2048
#define BATCH  2
#define DM     1024
#define NHEAD  16
#define DHEAD  64
#define WIN    256
#define MROWS  4096

#define PPAD 68     // f32 LDS row stride for attn P

// gemm_qkv tile geometry (R13, measured-best class ~43 us): 256x192, BK=64,
// 8 waves as 4M x 2N (wave 64x96). dbuf 112 KB LDS, one barrier per K-tile.
#define BM 256
#define BN 192
#define BK 64
#define NKT (DM / BK)          // 16 K-tiles

// gemm_out tile geometry (R14): 128x64, BK=64, 4 waves as 2x2 (64x32 wave)
#define OM 128
#define ON 64

typedef __attribute__((ext_vector_type(8))) short bf16x8;
typedef __attribute__((ext_vector_type(4))) float f32x4;

__device__ __forceinline__ unsigned short f2b(float f) {   // RNE
    unsigned int u = __float_as_uint(f);
    return (unsigned short)((u + 0x7fffu + ((u >> 16) & 1u)) >> 16);
}
__device__ __forceinline__ void gld16(const void* g, void* l) {
    __builtin_amdgcn_global_load_lds(
        (const __attribute__((address_space(1))) void*)g,
        (__attribute__((address_space(3))) void*)l, 16, 0, 0);
}
__device__ __forceinline__ bf16x8 pack8(float4 a, float4 b) {
    bf16x8 r;
    r[0] = (short)f2b(a.x); r[1] = (short)f2b(a.y);
    r[2] = (short)f2b(a.z); r[3] = (short)f2b(a.w);
    r[4] = (short)f2b(b.x); r[5] = (short)f2b(b.y);
    r[6] = (short)f2b(b.z); r[7] = (short)f2b(b.w);
    return r;
}

// ---------------------------------------------------------------------------
// R17 twcvt4 (measured passing R8): weight transpose (z=0..3) + x fp32->bf16
// convert (z=4), one launch.
// ---------------------------------------------------------------------------
__global__ __launch_bounds__(256)
void twcvt4(const float* __restrict__ W0, const float* __restrict__ W1,
            const float* __restrict__ W2, const float* __restrict__ W3,
            const float* __restrict__ x,
            unsigned short* __restrict__ T0, unsigned short* __restrict__ T1,
            unsigned short* __restrict__ T2, unsigned short* __restrict__ T3,
            unsigned short* __restrict__ xb)
{
    const int zz = blockIdx.z;
    if (zz == 4) {
        const int flat = blockIdx.y * 32 + blockIdx.x;
        const int base = flat * 4096 + threadIdx.x * 4;
#pragma unroll
        for (int p = 0; p < 4; ++p) {
            const int i = base + p * 1024;
            float4 f = *(const float4*)(x + i);
            ushort4 o;
            o.x = f2b(f.x); o.y = f2b(f.y); o.z = f2b(f.z); o.w = f2b(f.w);
            *(ushort4*)(xb + i) = o;
        }
        return;
    }
    const float* W = (zz == 0) ? W0 : (zz == 1) ? W1 : (zz == 2) ? W2 : W3;
    unsigned short* WT = (zz == 0) ? T0 : (zz == 1) ? T1 : (zz == 2) ? T2 : T3;

    __shared__ float t32[32][33];
    const int bx = blockIdx.x * 32;
    const int by = blockIdx.y * 32;
    const int c  = threadIdx.x & 31;
    const int r0 = threadIdx.x >> 5;
#pragma unroll
    for (int p = 0; p < 4; ++p)
        t32[r0 + 8 * p][c] = W[(size_t)(by + r0 + 8 * p) * DM + bx + c];
    __syncthreads();
#pragma unroll
    for (int p = 0; p < 4; ++p)
        WT[(size_t)(bx + r0 + 8 * p) * DM + by + c] = f2b(t32[c][r0 + 8 * p]);
}

// ---------------------------------------------------------------------------
// R13 gemm_qkv (measured-best class, part of the session-best 169.4 total):
// 256x192, BK=64, 8 waves as 4M x 2N (wave 64x96). One barrier per K-tile:
//   { kk0 frag reads (10 b128) | stage tile kt+1 (7 gld16) | 24 MFMA |
//     kk1 frag reads | 24 MFMA | vmcnt(0) | s_barrier }.
// XOR chunk swizzle (chunk ^= row&7) on staging SOURCE + read addr; LDS
// dest linear (global_load_lds requirement); 0 bank conflicts measured.
// WAR safe: reads of buf[cur] complete (lgkm before last MFMA) before the
// trailing barrier; staging into buf[cur] only in the next iteration.
// ---------------------------------------------------------------------------
__global__ __launch_bounds__(512, 2)
void gemm_qkv(const unsigned short* __restrict__ A,
              const unsigned short* __restrict__ BT,
              const float* __restrict__ b0,
              const float* __restrict__ b1,
              const float* __restrict__ b2,
              const float* __restrict__ beta,
              unsigned short* __restrict__ Cb)
{
    __shared__ unsigned short Ab[2][BM * BK];   // 2 x 32 KB
    __shared__ unsigned short Bb[2][BN * BK];   // 2 x 24 KB

    const int t   = threadIdx.x;
    const int ln  = t & 63;
    const int wv  = t >> 6;          // 0..7
    const int wr  = wv & 3;          // 4M -> 64-row slice
    const int wc  = wv >> 2;         // 2N -> 96-col slice
    const int m16 = ln & 15;
    const int g   = ln >> 4;         // 0..3
    const int sw  = m16 & 7;         // read-side swizzle key (row & 7)

    const int rowBase = blockIdx.y * BM;
    const int colBase = blockIdx.x * BN;

    const int sr  = t >> 3;                   // 0..63
    const int scx = (t & 7) ^ (sr & 7);       // pre-swizzled global col-chunk
    const size_t gOff = (size_t)sr * DM + scx * 8;
    const int    ldOff = t * 8;               // shorts (t*16 bytes)

    f32x4 acc[4][6];
#pragma unroll
    for (int u = 0; u < 4; ++u)
#pragma unroll
        for (int v = 0; v < 6; ++v)
            acc[u][v] = (f32x4){0.f, 0.f, 0.f, 0.f};

    const unsigned short* aBase = A  + (size_t)rowBase * DM + gOff;
    const unsigned short* bBase = BT + (size_t)colBase * DM + gOff;

    // prologue: stage K-tile 0 into buffer 0, full drain once
    {
#pragma unroll
        for (int cb = 0; cb < 3; ++cb)
            gld16(bBase + (size_t)cb * 64 * DM, &Bb[0][cb * 4096 + ldOff]);
#pragma unroll
        for (int ca = 0; ca < 4; ++ca)
            gld16(aBase + (size_t)ca * 64 * DM, &Ab[0][ca * 4096 + ldOff]);
        asm volatile("s_waitcnt vmcnt(0)" ::: "memory");
        __builtin_amdgcn_s_barrier();
        __builtin_amdgcn_sched_barrier(0);
    }

    for (int kt = 0; kt < NKT; ++kt) {
        const int cur = kt & 1;
        const unsigned short* Ac = Ab[cur];
        const unsigned short* Bc = Bb[cur];
        unsigned short* An = Ab[cur ^ 1];
        unsigned short* Bn = Bb[cur ^ 1];
        const bool hn = (kt < NKT - 1);
        const unsigned short* aS = aBase + (size_t)(kt + 1) * BK;
        const unsigned short* bS = bBase + (size_t)(kt + 1) * BK;

        // ---- kk = 0 fragment reads (10 x ds_read_b128) ----
        bf16x8 af0[4], bf0[6];
#pragma unroll
        for (int u = 0; u < 4; ++u)
            af0[u] = *(const bf16x8*)&Ac[(wr * 64 + u * 16 + m16) * BK + ((g ^ sw) * 8)];
#pragma unroll
        for (int v = 0; v < 6; ++v)
            bf0[v] = *(const bf16x8*)&Bc[(wc * 96 + v * 16 + m16) * BK + ((g ^ sw) * 8)];

        // ---- stage ALL of tile kt+1 now (7 loads, waited at end of iter) ----
        if (hn) {
            gld16(bS,                    &Bn[ldOff]);
            gld16(bS + (size_t)64 * DM,  &Bn[4096 + ldOff]);
            gld16(bS + (size_t)128 * DM, &Bn[2 * 4096 + ldOff]);
            gld16(aS,                    &An[ldOff]);
            gld16(aS + (size_t)64 * DM,  &An[4096 + ldOff]);
            gld16(aS + (size_t)128 * DM, &An[2 * 4096 + ldOff]);
            gld16(aS + (size_t)192 * DM, &An[3 * 4096 + ldOff]);
        }

        __builtin_amdgcn_s_setprio(1);
#pragma unroll
        for (int u = 0; u < 4; ++u)
#pragma unroll
            for (int v = 0; v < 6; ++v)
                acc[u][v] = __builtin_amdgcn_mfma_f32_16x16x32_bf16(
                    af0[u], bf0[v], acc[u][v], 0, 0, 0);
        __builtin_amdgcn_s_setprio(0);

        // ---- kk = 1 fragment reads ----
        bf16x8 af1[4], bf1[6];
#pragma unroll
        for (int u = 0; u < 4; ++u)
            af1[u] = *(const bf16x8*)&Ac[(wr * 64 + u * 16 + m16) * BK + (((4 | g) ^ sw) * 8)];
#pragma unroll
        for (int v = 0; v < 6; ++v)
            bf1[v] = *(const bf16x8*)&Bc[(wc * 96 + v * 16 + m16) * BK + (((4 | g) ^ sw) * 8)];

        __builtin_amdgcn_s_setprio(1);
#pragma unroll
        for (int u = 0; u < 4; ++u)
#pragma unroll
            for (int v = 0; v < 6; ++v)
                acc[u][v] = __builtin_amdgcn_mfma_f32_16x16x32_bf16(
                    af1[u], bf1[v], acc[u][v], 0, 0, 0);
        __builtin_amdgcn_s_setprio(0);

        if (hn)
            asm volatile("s_waitcnt vmcnt(0)" ::: "memory");
        __builtin_amdgcn_s_barrier();
        __builtin_amdgcn_sched_barrier(0);
    }

    // epilogue — proven math; sec per fragment (wave-uniform per fragment).
    const int q4 = g * 4;
#pragma unroll
    for (int v = 0; v < 6; ++v) {
        const int col = colBase + wc * 96 + v * 16 + m16;
        const int sec = col >> 10;
        const int h   = (col >> 6) & (NHEAD - 1);
        const int dh  = col & 63;
        if (sec < 2) {
            const float bi = (sec == 0 ? b0 : b1)[col & (DM - 1)];
            const float sc = (sec == 0) ? 0.125f * __expf(-beta[h]) : 1.0f;
            unsigned short* base = Cb + (size_t)sec * MROWS * DM;
#pragma unroll
            for (int u = 0; u < 4; ++u)
#pragma unroll
                for (int r = 0; r < 4; ++r) {
                    const int row = rowBase + wr * 64 + u * 16 + q4 + r;
                    const int s = row >> 1, bb = row & 1;
                    const int z = bb * NHEAD + h;
                    base[((size_t)z * S_LEN + s) * DHEAD + dh] =
                        f2b((acc[u][v][r] + bi) * sc);
                }
        } else {
            unsigned short* vtb = Cb + (size_t)2 * MROWS * DM;
            const float bi = b2[col & (DM - 1)];
#pragma unroll
            for (int u = 0; u < 4; ++u) {
                const int row0 = rowBase + wr * 64 + u * 16 + q4;
                const int s0   = row0 >> 1;
                ushort2 p0, p1;
                p0.x = f2b(acc[u][v][0] + bi);   // bb=0, s0
                p0.y = f2b(acc[u][v][2] + bi);   // bb=0, s0+1
                p1.x = f2b(acc[u][v][1] + bi);   // bb=1, s0
                p1.y = f2b(acc[u][v][3] + bi);   // bb=1, s0+1
                *(ushort2*)(vtb + ((size_t)(h * DHEAD + dh) * S_LEN + s0)) = p0;
                *(ushort2*)(vtb + ((size_t)((NHEAD + h) * DHEAD + dh) * S_LEN + s0)) = p1;
            }
        }
    }
}

// ---------------------------------------------------------------------------
// R14 gemm_out (measured passing R8/R10): 128x64 tile, BK=64, 4 waves as
// 2x2 (wave 64x32). 512 blocks = 2 blocks/CU. One-barrier counted schedule.
// ---------------------------------------------------------------------------
__global__ __launch_bounds__(256, 2)
void gemm_out(const unsigned short* __restrict__ A,
              const unsigned short* __restrict__ BT,
              const float* __restrict__ bias,
              float* __restrict__ Cf)
{
    __shared__ unsigned short As[2][OM * 64];   // 2 x 16 KB
    __shared__ unsigned short Bs[2][ON * 64];   // 2 x 8 KB

    const int t  = threadIdx.x;
    const int wv = t >> 6, ln = t & 63;
    const int wr = wv >> 1, wc = wv & 1;        // 2x2, wave 64x32
    const int m16 = ln & 15, g = ln >> 4;
    const int sw  = m16 & 7;

    const int rowBase = blockIdx.y * OM;
    const int colBase = blockIdx.x * ON;

    const int sr  = t >> 3;                   // 0..31
    const int scx = (t & 7) ^ (sr & 7);
    const size_t gOff = (size_t)sr * DM + scx * 8;
    const int    ldOff = t * 8;

    f32x4 acc[4][2];
#pragma unroll
    for (int u = 0; u < 4; ++u)
#pragma unroll
        for (int v = 0; v < 2; ++v)
            acc[u][v] = (f32x4){0.f, 0.f, 0.f, 0.f};

    // prologue: stage K-tile 0
    {
        const unsigned short* a0 = A  + (size_t)rowBase * DM + gOff;
        const unsigned short* bt = BT + (size_t)colBase * DM + gOff;
#pragma unroll
        for (int j = 0; j < 4; ++j)
            gld16(a0 + (size_t)(j * 32) * DM, &As[0][j * 2048 + ldOff]);
#pragma unroll
        for (int j = 0; j < 2; ++j)
            gld16(bt + (size_t)(j * 32) * DM, &Bs[0][j * 2048 + ldOff]);
        asm volatile("s_waitcnt vmcnt(0)" ::: "memory");
        __builtin_amdgcn_s_barrier();
        __builtin_amdgcn_sched_barrier(0);
    }

    for (int kt = 0; kt < DM / 64; ++kt) {
        const int cur = kt & 1;
        const unsigned short* Ac = As[cur];
        const unsigned short* Bc = Bs[cur];
        unsigned short* An = As[cur ^ 1];
        unsigned short* Bn = Bs[cur ^ 1];
        const bool hn = (kt < DM / 64 - 1);
        const unsigned short* aS = A  + (size_t)rowBase * DM + (kt + 1) * 64 + gOff;
        const unsigned short* bS = BT + (size_t)colBase * DM + (kt + 1) * 64 + gOff;

        bf16x8 af0[4], bf0[2];
#pragma unroll
        for (int u = 0; u < 4; ++u)
            af0[u] = *(const bf16x8*)&Ac[(wr * 64 + u * 16 + m16) * 64 + ((g ^ sw) * 8)];
#pragma unroll
        for (int v = 0; v < 2; ++v)
            bf0[v] = *(const bf16x8*)&Bc[(wc * 32 + v * 16 + m16) * 64 + ((g ^ sw) * 8)];

        if (hn) {
#pragma unroll
            for (int j = 0; j < 4; ++j)
                gld16(aS + (size_t)(j * 32) * DM, &An[j * 2048 + ldOff]);
#pragma unroll
            for (int j = 0; j < 2; ++j)
                gld16(bS + (size_t)(j * 32) * DM, &Bn[j * 2048 + ldOff]);
        }

        __builtin_amdgcn_s_setprio(1);
#pragma unroll
        for (int u = 0; u < 4; ++u)
#pragma unroll
            for (int v = 0; v < 2; ++v)
                acc[u][v] = __builtin_amdgcn_mfma_f32_16x16x32_bf16(
                    af0[u], bf0[v], acc[u][v], 0, 0, 0);
        __builtin_amdgcn_s_setprio(0);

        bf16x8 af1[4], bf1[2];
#pragma unroll
        for (int u = 0; u < 4; ++u)
            af1[u] = *(const bf16x8*)&Ac[(wr * 64 + u * 16 + m16) * 64 + (((4 | g) ^ sw) * 8)];
#pragma unroll
        for (int v = 0; v < 2; ++v)
            bf1[v] = *(const bf16x8*)&Bc[(wc * 32 + v * 16 + m16) * 64 + (((4 | g) ^ sw) * 8)];

        __builtin_amdgcn_s_setprio(1);
#pragma unroll
        for (int u = 0; u < 4; ++u)
#pragma unroll
            for (int v = 0; v < 2; ++v)
                acc[u][v] = __builtin_amdgcn_mfma_f32_16x16x32_bf16(
                    af1[u], bf1[v], acc[u][v], 0, 0, 0);
        __builtin_amdgcn_s_setprio(0);

        if (hn)
            asm volatile("s_waitcnt vmcnt(0)" ::: "memory");
        __builtin_amdgcn_s_barrier();
        __builtin_amdgcn_sched_barrier(0);
    }

    const int q4 = g * 4;
#pragma unroll
    for (int v = 0; v < 2; ++v) {
        const int col = colBase + wc * 32 + v * 16 + m16;
        const float bi = bias[col];
#pragma unroll
        for (int u = 0; u < 4; ++u)
#pragma unroll
            for (int r = 0; r < 4; ++r) {
                const int row = rowBase + wr * 64 + u * 16 + q4 + r;
                Cf[(size_t)row * DM + col] = acc[u][v][r] + bi;
            }
    }
}

// ---------------------------------------------------------------------------
// R14 attn (measured passing R4-R10): async dbuf K/V staging, one barrier
// per tile, wave-private P round-trip (lgkm only). No online max (scores
// bounded by the 0.125*exp(-beta) pre-scale); sink l0=1; exp(-1e30)==0.
// ---------------------------------------------------------------------------
__global__ __launch_bounds__(256, 3)
void attn_mfma(const unsigned short* __restrict__ q,
               const unsigned short* __restrict__ k,
               const unsigned short* __restrict__ vt,
               unsigned short* __restrict__ ao)
{
    __shared__ unsigned short Ks[2][64 * 64];   // [key][d-chunk swz]
    __shared__ unsigned short Vs[2][64 * 64];   // [dh][key-chunk swz]
    __shared__ float Ps[64][PPAD];              // [wave*16 + qrow][key]

    const int t   = threadIdx.x;
    const int wv  = t >> 6, ln = t & 63;
    const int m16 = ln & 15, g = ln >> 4;
    const int sw  = m16 & 7;
    const int z   = blockIdx.y;
    const int q0  = blockIdx.x * 64;
    const size_t zbase = (size_t)z * S_LEN * DHEAD;

    const int sr  = t >> 3;                   // 0..31
    const int scx = (t & 7) ^ (sr & 7);
    const unsigned short* kS = k  + zbase + (size_t)sr * DHEAD + scx * 8;
    const unsigned short* vS = vt + ((size_t)z * DHEAD + sr) * S_LEN + scx * 8;
    const int ldOff = t * 8;                  // shorts

    const unsigned short* qrow = q + zbase + (size_t)(q0 + wv * 16 + m16) * DHEAD;
    bf16x8 qf0 = *(const bf16x8*)(qrow + g * 8);
    bf16x8 qf1 = *(const bf16x8*)(qrow + 32 + g * 8);

    f32x4 oacc[4];
#pragma unroll
    for (int v4 = 0; v4 < 4; ++v4) oacc[v4] = (f32x4){0.f, 0.f, 0.f, 0.f};
    float lr[4];
#pragma unroll
    for (int r = 0; r < 4; ++r) lr[r] = 1.f;   // sink: exp(0)

    const int c0 = (blockIdx.x < 4) ? (4 - (int)blockIdx.x) : 0;

    // prologue: stage tile c0 into buffer 0
    {
        const int kb = q0 - 256 + c0 * 64;
        gld16(kS + (size_t)kb * DHEAD,        &Ks[0][ldOff]);
        gld16(kS + (size_t)(kb + 32) * DHEAD, &Ks[0][2048 + ldOff]);
        gld16(vS + kb,                        &Vs[0][ldOff]);
        gld16(vS + (size_t)32 * S_LEN + kb,   &Vs[0][2048 + ldOff]);
        asm volatile("s_waitcnt vmcnt(0)" ::: "memory");
        __builtin_amdgcn_s_barrier();
        __builtin_amdgcn_sched_barrier(0);
    }

    for (int c = c0; c < 5; ++c) {
        const int cur = (c - c0) & 1;
        const int kb  = q0 - 256 + c * 64;
        const bool hn = (c < 4);

        // stage next tile into buf cur^1 (waited at end of this iter)
        if (hn) {
            const int kn = kb + 64;
            gld16(kS + (size_t)kn * DHEAD,        &Ks[cur ^ 1][ldOff]);
            gld16(kS + (size_t)(kn + 32) * DHEAD, &Ks[cur ^ 1][2048 + ldOff]);
            gld16(vS + kn,                        &Vs[cur ^ 1][ldOff]);
            gld16(vS + (size_t)32 * S_LEN + kn,   &Vs[cur ^ 1][2048 + ldOff]);
        }

        // S = Q K^T
        f32x4 sacc[4];
#pragma unroll
        for (int v4 = 0; v4 < 4; ++v4) {
            sacc[v4] = (f32x4){0.f, 0.f, 0.f, 0.f};
            bf16x8 kf0 = *(const bf16x8*)&Ks[cur][(v4 * 16 + m16) * 64 + ((g ^ sw) * 8)];
            sacc[v4] = __builtin_amdgcn_mfma_f32_16x16x32_bf16(qf0, kf0, sacc[v4], 0, 0, 0);
            bf16x8 kf1 = *(const bf16x8*)&Ks[cur][(v4 * 16 + m16) * 64 + (((4 | g) ^ sw) * 8)];
            sacc[v4] = __builtin_amdgcn_mfma_f32_16x16x32_bf16(qf1, kf1, sacc[v4], 0, 0, 0);
        }

        // mask + exp + row-sum (no max): P -> LDS (wave-private rows)
        const bool mhi = (c == 4), mlo = (c == 0);
#pragma unroll
        for (int r = 0; r < 4; ++r) {
            const int ig = q0 + wv * 16 + g * 4 + r;
            float rsum = 0.f;
#pragma unroll
            for (int v4 = 0; v4 < 4; ++v4) {
                const int jg = kb + v4 * 16 + m16;
                float x = sacc[v4][r];
                const bool valid = (!mhi || jg <= ig) && (!mlo || jg >= ig - (WIN - 1));
                x = valid ? x : -1e30f;
                const float pp = __expf(x);     // masked -> exactly 0
                Ps[wv * 16 + g * 4 + r][v4 * 16 + m16] = pp;
                rsum += pp;
            }
#pragma unroll
            for (int off = 1; off < 16; off <<= 1)
                rsum += __shfl_xor(rsum, off, 64);
            lr[r] += rsum;
        }

        // wave-private round-trip: LDS drain only, no block barrier
        asm volatile("s_waitcnt lgkmcnt(0)" ::: "memory");
        __builtin_amdgcn_sched_barrier(0);

        // O += P V
        const float* prow = &Ps[wv * 16 + m16][0];
        bf16x8 pf0 = pack8(*(const float4*)(prow + g * 8),
                           *(const float4*)(prow + g * 8 + 4));
        bf16x8 pf1 = pack8(*(const float4*)(prow + 32 + g * 8),
                           *(const float4*)(prow + 32 + g * 8 + 4));
#pragma unroll
        for (int v4 = 0; v4 < 4; ++v4) {
            bf16x8 vf0 = *(const bf16x8*)&Vs[cur][(v4 * 16 + m16) * 64 + ((g ^ sw) * 8)];
            oacc[v4] = __builtin_amdgcn_mfma_f32_16x16x32_bf16(pf0, vf0, oacc[v4], 0, 0, 0);
            bf16x8 vf1 = *(const bf16x8*)&Vs[cur][(v4 * 16 + m16) * 64 + (((4 | g) ^ sw) * 8)];
            oacc[v4] = __builtin_amdgcn_mfma_f32_16x16x32_bf16(pf1, vf1, oacc[v4], 0, 0, 0);
        }

        if (hn) {
            asm volatile("s_waitcnt vmcnt(0)" ::: "memory");
            __builtin_amdgcn_s_barrier();
            __builtin_amdgcn_sched_barrier(0);
        }
    }

    const int bb = z >> 4, h = z & 15;
#pragma unroll
    for (int r = 0; r < 4; ++r) {
        const int ig  = q0 + wv * 16 + g * 4 + r;
        const float inv = 1.f / lr[r];
#pragma unroll
        for (int v4 = 0; v4 < 4; ++v4)
            ao[(size_t)(ig * BATCH + bb) * DM + h * DHEAD + v4 * 16 + m16] =
                f2b(oacc[v4][r] * inv);
    }
}

// ---------------------------------------------------------------------------
extern "C" void kernel_launch(void* const* d_in, const int* in_sizes, int n_in,
                              void* d_out, int out_size, void* d_ws, size_t ws_size,
                              hipStream_t stream)
{
    const float* x    = (const float*)d_in[0];
    const float* beta = (const float*)d_in[1];
    const float* Wq   = (const float*)d_in[2];
    const float* bq   = (const float*)d_in[3];
    const float* Wk   = (const float*)d_in[4];
    const float* bk   = (const float*)d_in[5];
    const float* Wv   = (const float*)d_in[6];
    const float* bv   = (const float*)d_in[7];
    const float* Wo   = (const float*)d_in[8];
    const float* bo   = (const float*)d_in[9];
    float* out = (float*)d_out;

    unsigned short* w = (unsigned short*)d_ws;
    const size_t seg = (size_t)MROWS * DM;      // 4M elems
    unsigned short* qb  = w;                    // q (z,s,dh)
    unsigned short* kb  = w + seg;              // k (z,s,dh)
    unsigned short* vtb = w + 2 * seg;          // v^T (z,dh,s) -- direct from QKV
    unsigned short* ab  = w + 3 * seg;          // attn out, row-major
    unsigned short* xb  = w + 4 * seg;          // x bf16
    unsigned short* wtq = w + 5 * seg;          // WqT|WkT|WvT|WoT contiguous
    unsigned short* wtk = wtq + (size_t)DM * DM;
    unsigned short* wtv = wtk + (size_t)DM * DM;
    unsigned short* wto = wtv + (size_t)DM * DM;

    // weight transpose (z=0..3) + x convert (z=4), one launch
    twcvt4<<<dim3(32, 32, 5), 256, 0, stream>>>(
        Wq, Wk, Wv, Wo, x, wtq, wtk, wtv, wto, xb);

    // fused Q+K+V projection: 256x192 tiles -> 16x16 = 256 blocks (1/CU)
    gemm_qkv<<<dim3(3072 / BN, MROWS / BM), 512, 0, stream>>>(
        xb, wtq, bq, bk, bv, beta, qb);

    attn_mfma<<<dim3(S_LEN / 64, BATCH * NHEAD), 256, 0, stream>>>(qb, kb, vtb, ab);

    // output projection: 128x64 tiles -> 16x32 = 512 blocks (2/CU)
    gemm_out<<<dim3(DM / ON, MROWS / OM), 256, 0, stream>>>(ab, wto, bo, out);
}